// Round 1
// baseline (322.792 us; speedup 1.0000x reference)
//
#include <hip/hip_runtime.h>
#include <hip/hip_bf16.h>

typedef __attribute__((ext_vector_type(4))) float f32x4;
typedef __attribute__((ext_vector_type(8))) short bf16x8;
typedef __attribute__((ext_vector_type(4))) short s16x4;

#define C_DIM 512
#define N_PIX 2304
#define N_BATCH 8
#define ATT_SCALE 0.04419417382415922f
#define NJB 9                       // N_PIX / 256 (s_vp j-tiles)

typedef __attribute__((address_space(3))) unsigned int lds_u32;
typedef const __attribute__((address_space(1))) unsigned int glob_u32;

__device__ __forceinline__ void gl2lds16(const __hip_bfloat16* g, __hip_bfloat16* l)
{
    __builtin_amdgcn_global_load_lds((glob_u32*)g, (lds_u32*)l, 16, 0, 0);
}

// ---------------------------------------------------------------------------
// Merged S + V' dispatch, 256x256 8-phase schedule (T2+T3+T4+T5).
// 1-D grid, NS batches (lin%NS -> XCD pin), t=lin/NS:
//   t < 81 : S-block   : Pu[n,m] = exp(SC * sum_o Qt[n,o]Kt[m,o]), rp partials
//   t >= 81: V'-block  : Vp[o,m] = sum_c Wo[o,c]*Vt[m,c]
// K=512 -> 8 K-tiles of BK=64. 8 waves (2M x 4N), per-wave 128x64 C.
// LDS 128 KiB: LA/LB [2 dbuf][256][64], XOR chunk-swizzled.
// Per K-tile: 4 phases, quadrant order (0,0),(0,1),(1,1),(1,0).
// Stage units: A-unit h = rows {q*128+h*64 .. +63}, B-unit b = bit5(row)==b.
// Steady-state staging: q0->A1(t+1), q1->B0(t+1), q2->A0(t+2), q3->B1(t+2);
// vmcnt(4) once per tile (2 half-tiles stay in flight across barriers).
// ---------------------------------------------------------------------------

#define BAR()  __builtin_amdgcn_s_barrier()
#define LGK0() asm volatile("s_waitcnt lgkmcnt(0)" ::: "memory")
#define VM4()  asm volatile("s_waitcnt vmcnt(4)" ::: "memory")
#define VM0()  asm volatile("s_waitcnt vmcnt(0)" ::: "memory")
#define PRIO(p) __builtin_amdgcn_s_setprio(p)

#define STAGE_A(dd, hh, tk) do { \
    _Pragma("unroll") \
    for (int ss = 0; ss < 2; ++ss) { \
        const int ur0 = wave * 16 + ss * 8; \
        const int row0 = ((ur0 >> 6) << 7) + (hh) * 64 + (ur0 & 63); \
        gl2lds16(gA + (size_t)row0 * C_DIM + (tk) * 64, \
                 (__hip_bfloat16*)&LA[dd][row0 * 64]); \
    } } while (0)

#define STAGE_B(dd, bb, tk) do { \
    _Pragma("unroll") \
    for (int ss = 0; ss < 2; ++ss) { \
        const int ur0 = wave * 16 + ss * 8; \
        const int row0 = ((ur0 >> 5) << 6) + (bb) * 32 + (ur0 & 31); \
        gl2lds16(gB + (size_t)row0 * C_DIM + (tk) * 64, \
                 (__hip_bfloat16*)&LB[dd][row0 * 64]); \
    } } while (0)

#define LOAD_A(dd, hh) do { \
    _Pragma("unroll") \
    for (int tt = 0; tt < 4; ++tt) { \
        const int rb = (wr * 128 + (hh) * 64 + tt * 16 + fr) * 64; \
        _Pragma("unroll") \
        for (int kk = 0; kk < 2; ++kk) \
            aF[tt][kk] = *(const bf16x8*)(&LA[dd][rb + (((kk * 4 + fq) ^ sw) << 3)]); \
    } } while (0)

#define LOAD_B(dd, bb, dst) do { \
    _Pragma("unroll") \
    for (int s2 = 0; s2 < 2; ++s2) { \
        const int rb = (wc * 64 + (bb) * 32 + s2 * 16 + fr) * 64; \
        _Pragma("unroll") \
        for (int kk = 0; kk < 2; ++kk) \
            dst[s2][kk] = *(const bf16x8*)(&LB[dd][rb + (((kk * 4 + fq) ^ sw) << 3)]); \
    } } while (0)

#define MFMA_Q(HH, BB, bsrc) do { \
    _Pragma("unroll") \
    for (int tt = 0; tt < 4; ++tt) \
    _Pragma("unroll") \
    for (int s2 = 0; s2 < 2; ++s2) \
    _Pragma("unroll") \
    for (int kk = 0; kk < 2; ++kk) \
        acc[(HH) * 4 + tt][(BB) * 2 + s2] = __builtin_amdgcn_mfma_f32_16x16x32_bf16( \
            aF[tt][kk], bsrc[s2][kk], acc[(HH) * 4 + tt][(BB) * 2 + s2], 0, 0, 0); \
    } while (0)

template<int NS>
__global__ __launch_bounds__(512, 2)
void s_vp(const __hip_bfloat16* __restrict__ Qt, const __hip_bfloat16* __restrict__ Kt,
          __hip_bfloat16* __restrict__ Pu, float* __restrict__ rp,
          const __hip_bfloat16* __restrict__ wo, const __hip_bfloat16* __restrict__ Vt,
          __hip_bfloat16* __restrict__ Vp, int bz_off, long sPu)
{
    __shared__ __hip_bfloat16 LA[2][256 * 64];
    __shared__ __hip_bfloat16 LB[2][256 * 64];

    const int lin = blockIdx.x;
    const int bz  = lin % NS + bz_off;
    const int t   = lin / NS;
    const bool is_s = (t < 81);

    int ib, jb;
    const __hip_bfloat16 *A, *B;
    __hip_bfloat16* D;
    const long sQ = (long)N_PIX * C_DIM;
    if (is_s) {
        ib = t / 9; jb = t % 9;
        A = Qt + (size_t)bz * sQ;
        B = Kt + (size_t)bz * sQ;
        D = Pu + (size_t)bz * (size_t)sPu;
    } else {
        int u = t - 81;               // 0..17
        ib = u / 9; jb = u % 9;
        A = wo;
        B = Vt + (size_t)bz * sQ;
        D = Vp + (size_t)bz * sQ;
    }
    const int i0 = ib * 256;
    const int j0 = jb * 256;

    const int tid  = threadIdx.x;
    const int lane = tid & 63;
    const int wave = tid >> 6;

    const int lrow = lane >> 3;
    const int lcs  = (lane & 7) ^ lrow;           // XOR chunk swizzle (store side)
    const __hip_bfloat16* gA = A + (size_t)(i0 + lrow) * C_DIM + lcs * 8;
    const __hip_bfloat16* gB = B + (size_t)(j0 + lrow) * C_DIM + lcs * 8;

    const int fr = lane & 15;
    const int fq = lane >> 4;
    const int sw = fr & 7;                        // row&7 on read side
    const int wr = wave >> 2;                     // 0..1 (row wave)
    const int wc = wave & 3;                      // 0..3 (col wave)

    f32x4 acc[8][4];
#pragma unroll
    for (int a = 0; a < 8; ++a)
#pragma unroll
        for (int b = 0; b < 4; ++b)
            acc[a][b] = (f32x4){0.f, 0.f, 0.f, 0.f};

    bf16x8 aF[4][2], bF0[2][2], bF1[2][2];

    // --- prologue: tile0 (all 4 halves) + tile1 {A0,B1}; vmcnt(4) -> tile0 landed
    STAGE_A(0, 0, 0); STAGE_B(0, 0, 0); STAGE_B(0, 1, 0); STAGE_A(0, 1, 0);
    STAGE_A(1, 0, 1); STAGE_B(1, 1, 1);
    VM4();
    BAR();

    // --- main loop: K-tiles 0..5 (NT-2 = 6), full staging, counted vmcnt
    for (int kt = 0; kt < 6; ++kt) {
        const int d = kt & 1, e = d ^ 1;
        // phase 0: quadrant (0,0)
        LOAD_A(d, 0); LOAD_B(d, 0, bF0);
        STAGE_A(e, 1, kt + 1);
        BAR(); LGK0();
        PRIO(1); MFMA_Q(0, 0, bF0); PRIO(0);
        BAR();
        // phase 1: quadrant (0,1)
        LOAD_B(d, 1, bF1);
        STAGE_B(e, 0, kt + 1);
        BAR(); LGK0();
        PRIO(1); MFMA_Q(0, 1, bF1); PRIO(0);
        BAR();
        // phase 2: quadrant (1,1)
        LOAD_A(d, 1);
        STAGE_A(d, 0, kt + 2);
        BAR(); LGK0();
        PRIO(1); MFMA_Q(1, 1, bF1); PRIO(0);
        BAR();
        // phase 3: quadrant (1,0)
        STAGE_B(d, 1, kt + 2);
        VM4();                         // tile kt+1 fully landed; 2 half-tiles in flight
        BAR();
        PRIO(1); MFMA_Q(1, 0, bF0); PRIO(0);
        BAR();
    }
    // --- K-tile 6 (buf 0): stage only tile-7 {A1,B0}; drain at end
    {
        LOAD_A(0, 0); LOAD_B(0, 0, bF0);
        STAGE_A(1, 1, 7);
        BAR(); LGK0();
        PRIO(1); MFMA_Q(0, 0, bF0); PRIO(0);
        BAR();
        LOAD_B(0, 1, bF1);
        STAGE_B(1, 0, 7);
        BAR(); LGK0();
        PRIO(1); MFMA_Q(0, 1, bF1); PRIO(0);
        BAR();
        LOAD_A(0, 1);
        BAR(); LGK0();
        PRIO(1); MFMA_Q(1, 1, bF1); PRIO(0);
        BAR();
        VM0();                         // tile 7 fully landed
        BAR();
        PRIO(1); MFMA_Q(1, 0, bF0); PRIO(0);
        BAR();
    }
    // --- K-tile 7 (buf 1): no staging
    {
        LOAD_A(1, 0); LOAD_B(1, 0, bF0);
        BAR(); LGK0();
        PRIO(1); MFMA_Q(0, 0, bF0); PRIO(0);
        BAR();
        LOAD_B(1, 1, bF1);
        BAR(); LGK0();
        PRIO(1); MFMA_Q(0, 1, bF1); PRIO(0);
        BAR();
        LOAD_A(1, 1);
        BAR(); LGK0();
        PRIO(1); MFMA_Q(1, 1, bF1); PRIO(0);
        BAR();
        PRIO(1); MFMA_Q(1, 0, bF0); PRIO(0);
    }

    // --- epilogue
    if (is_s) {
        float rpart[8][4];
#pragma unroll
        for (int a = 0; a < 8; ++a)
#pragma unroll
            for (int r = 0; r < 4; ++r)
                rpart[a][r] = 0.f;
#pragma unroll
        for (int a = 0; a < 8; ++a) {
            const int grow = i0 + wr * 128 + a * 16 + fq * 4;
#pragma unroll
            for (int b = 0; b < 4; ++b) {
                const int col = j0 + wc * 64 + b * 16 + fr;
#pragma unroll
                for (int r = 0; r < 4; ++r) {
                    float v = __expf(acc[a][b][r] * ATT_SCALE);
                    rpart[a][r] += v;
                    D[(size_t)(grow + r) * N_PIX + col] = __float2bfloat16(v);
                }
            }
        }
        // reduce over fr (low 4 lane bits)
#pragma unroll
        for (int m = 1; m < 16; m <<= 1)
#pragma unroll
            for (int a = 0; a < 8; ++a)
#pragma unroll
                for (int r = 0; r < 4; ++r)
                    rpart[a][r] += __shfl_xor(rpart[a][r], m);
        float* rsl = (float*)&LA[0][0];
        __syncthreads();
        if (fr == 0) {
#pragma unroll
            for (int a = 0; a < 8; ++a)
#pragma unroll
                for (int r = 0; r < 4; ++r)
                    rsl[wave * 128 + a * 16 + fq * 4 + r] = rpart[a][r];
        }
        __syncthreads();
        if (tid < 256) {
            const int wr2 = tid >> 7, rl = tid & 127;
            float s = rsl[(wr2 * 4 + 0) * 128 + rl] + rsl[(wr2 * 4 + 1) * 128 + rl]
                    + rsl[(wr2 * 4 + 2) * 128 + rl] + rsl[(wr2 * 4 + 3) * 128 + rl];
            rp[((size_t)jb * N_BATCH + bz) * N_PIX + i0 + tid] = s;
        }
    } else {
#pragma unroll
        for (int a = 0; a < 8; ++a) {
            const int grow = i0 + wr * 128 + a * 16 + fq * 4;
#pragma unroll
            for (int b = 0; b < 4; ++b) {
                const int col = j0 + wc * 64 + b * 16 + fr;
#pragma unroll
                for (int r = 0; r < 4; ++r)
                    D[(size_t)(grow + r) * N_PIX + col] = __float2bfloat16(acc[a][b][r]);
            }
        }
    }
}

#undef STAGE_A
#undef STAGE_B
#undef LOAD_A
#undef LOAD_B
#undef MFMA_Q
#undef BAR
#undef LGK0
#undef VM4
#undef VM0
#undef PRIO

// ---------------------------------------------------------------------------
// PV + output: out[o,n] = rinv[n] * sum_m Vp[o,m]*Pu[n,m] + bo[o]  (fp32)
// 64x128 tile (i=o 8 tiles, j=n 18 tiles), K=N=2304. Grid NS*144, i-fast.
// rinv computed in-epilogue from rp partials (sum of NJB=9).
// ---------------------------------------------------------------------------
template<int NS>
__global__ __launch_bounds__(256)
void pv_out(const __hip_bfloat16* __restrict__ Vp, const __hip_bfloat16* __restrict__ Pu,
            float* __restrict__ out, const float* __restrict__ bo,
            const float* __restrict__ rp, int bz_off, long sPu)
{
    __shared__ __hip_bfloat16 As[64 * 64];
    __shared__ __hip_bfloat16 Bs[128 * 64];

    const int lin = blockIdx.x;
    const int bz  = lin % NS + bz_off;
    const int t   = lin / NS;
    const int ib  = t % 8;       // i-fast: consecutive blocks share Pu j-tile
    const int jb  = t / 8;
    const int i0  = ib * 64;
    const int j0  = jb * 128;

    const long sCN = (long)C_DIM * N_PIX;
    const __hip_bfloat16* A = Vp + (size_t)bz * sCN;   // [C,N] lda=N
    const __hip_bfloat16* B = Pu + (size_t)bz * (size_t)sPu; // [N,N] ldb=N
    float* D = out + (size_t)bz * sCN;

    const int tid  = threadIdx.x;
    const int lane = tid & 63;
    const int wave = tid >> 6;

    const int lrow = lane >> 3;
    const int lcs  = (lane & 7) ^ lrow;
    const __hip_bfloat16* ga = A + (size_t)(i0 + wave * 16 + lrow) * N_PIX + lcs * 8;
    const __hip_bfloat16* gb = B + (size_t)(j0 + wave * 32 + lrow) * N_PIX + lcs * 8;
    __hip_bfloat16* la = As + wave * 16 * 64;
    __hip_bfloat16* lb = Bs + wave * 32 * 64;

    const int fr = lane & 15;
    const int fq = lane >> 4;
    const int sw = fr & 7;
    const int wi = (wave >> 1) * 32;
    const int wj = (wave & 1) * 64;

    f32x4 acc[2][4];
#pragma unroll
    for (int a = 0; a < 2; ++a)
#pragma unroll
        for (int b = 0; b < 4; ++b)
            acc[a][b] = (f32x4){0.f, 0.f, 0.f, 0.f};

    for (int k0 = 0; k0 < N_PIX; k0 += 64) {
#pragma unroll
        for (int ss = 0; ss < 2; ++ss)
            gl2lds16(ga + (size_t)ss * 8 * N_PIX + k0, la + ss * 8 * 64);
#pragma unroll
        for (int ss = 0; ss < 4; ++ss)
            gl2lds16(gb + (size_t)ss * 8 * N_PIX + k0, lb + ss * 8 * 64);
        __syncthreads();

#pragma unroll
        for (int kk = 0; kk < 2; ++kk) {
            bf16x8 af[2], bfr[4];
            const int ca = ((kk * 4 + fq) ^ sw) << 3;
#pragma unroll
            for (int tt = 0; tt < 2; ++tt)
                af[tt]  = *(const bf16x8*)(&As[(wi + tt * 16 + fr) * 64 + ca]);
#pragma unroll
            for (int tt = 0; tt < 4; ++tt)
                bfr[tt] = *(const bf16x8*)(&Bs[(wj + tt * 16 + fr) * 64 + ca]);
#pragma unroll
            for (int a = 0; a < 2; ++a)
#pragma unroll
                for (int b = 0; b < 4; ++b)
                    acc[a][b] = __builtin_amdgcn_mfma_f32_16x16x32_bf16(
                        af[a], bfr[b], acc[a][b], 0, 0, 0);
        }
        __syncthreads();
    }

    // rinv per output column (4 cols/thread), from NJB rp partials each
    const int orow = fq * 4;
    float rjv[4];
#pragma unroll
    for (int b = 0; b < 4; ++b) {
        int j = j0 + wj + b * 16 + fr;
        float s = 0.f;
#pragma unroll
        for (int jj = 0; jj < NJB; ++jj)
            s += rp[((size_t)jj * N_BATCH + bz) * N_PIX + j];
        rjv[b] = 1.f / s;
    }

#pragma unroll
    for (int a = 0; a < 2; ++a) {
        int ibx = i0 + wi + a * 16 + orow;
#pragma unroll
        for (int r = 0; r < 4; ++r) {
            float bi = bo[ibx + r];
#pragma unroll
            for (int b = 0; b < 4; ++b) {
                int j = j0 + wj + b * 16 + fr;
                D[(size_t)(ibx + r) * N_PIX + j] = acc[a][b][r] * rjv[b] + bi;
            }
        }
    }
}

// ---------------------------------------------------------------------------
// Merged Q/K/V projection: 3 mats x 8 batches x 72 tiles = 1728 blocks.
// ---------------------------------------------------------------------------
__global__ __launch_bounds__(256)
void proj_qkv(const __hip_bfloat16* __restrict__ Xl,
              const __hip_bfloat16* __restrict__ Xg,
              const __hip_bfloat16* __restrict__ wgt,
              const float* __restrict__ bq, const float* __restrict__ bk,
              const float* __restrict__ bv,
              __hip_bfloat16* __restrict__ QKV)
{
    __shared__ __hip_bfloat16 As[128 * 64];
    __shared__ __hip_bfloat16 Bs[128 * 64];

    const int lin = blockIdx.x;
    const int s   = lin % 24;
    const int bz  = s & 7;
    const int mat = s >> 3;
    const int t   = lin / 24;
    const int j0  = (t & 3) * 128;
    const int i0  = (t >> 2) * 128;

    const __hip_bfloat16* Ab = ((mat == 0) ? Xl : Xg) + (size_t)bz * N_PIX * C_DIM;
    const __hip_bfloat16* Bb = wgt + (size_t)mat * C_DIM * C_DIM;
    const float* bias = (mat == 0) ? bq : (mat == 1) ? bk : bv;
    __hip_bfloat16* D = QKV + ((size_t)mat * N_BATCH + bz) * N_PIX * C_DIM;

    const int tid  = threadIdx.x;
    const int lane = tid & 63;
    const int wave = tid >> 6;

    const int lrow = lane >> 3;
    const int lcs  = (lane & 7) ^ lrow;
    const __hip_bfloat16* ga = Ab + (size_t)(i0 + wave * 32 + lrow) * C_DIM + lcs * 8;
    const __hip_bfloat16* gb = Bb + (size_t)(j0 + wave * 32 + lrow) * C_DIM + lcs * 8;
    __hip_bfloat16* la = As + wave * 32 * 64;
    __hip_bfloat16* lb = Bs + wave * 32 * 64;

    const int fr = lane & 15;
    const int fq = lane >> 4;
    const int sw = fr & 7;
    const int wi = (wave >> 1) * 64;
    const int wj = (wave & 1) * 64;

    f32x4 acc[4][4];
#pragma unroll
    for (int a = 0; a < 4; ++a)
#pragma unroll
        for (int b = 0; b < 4; ++b)
            acc[a][b] = (f32x4){0.f, 0.f, 0.f, 0.f};

    for (int k0 = 0; k0 < C_DIM; k0 += 64) {
#pragma unroll
        for (int ss = 0; ss < 4; ++ss) {
            gl2lds16(ga + (size_t)ss * 8 * C_DIM + k0, la + ss * 8 * 64);
            gl2lds16(gb + (size_t)ss * 8 * C_DIM + k0, lb + ss * 8 * 64);
        }
        __syncthreads();

#pragma unroll
        for (int kk = 0; kk < 2; ++kk) {
            bf16x8 af[4], bfr[4];
            const int ca = ((kk * 4 + fq) ^ sw) << 3;
#pragma unroll
            for (int tt = 0; tt < 4; ++tt) {
                af[tt]  = *(const bf16x8*)(&As[(wi + tt * 16 + fr) * 64 + ca]);
                bfr[tt] = *(const bf16x8*)(&Bs[(wj + tt * 16 + fr) * 64 + ca]);
            }
#pragma unroll
            for (int a = 0; a < 4; ++a)
#pragma unroll
                for (int b = 0; b < 4; ++b)
                    acc[a][b] = __builtin_amdgcn_mfma_f32_16x16x32_bf16(
                        af[a], bfr[b], acc[a][b], 0, 0, 0);
        }
        __syncthreads();
    }

    const int orow = fq * 4;
#pragma unroll
    for (int a = 0; a < 4; ++a) {
        int ibx = i0 + wi + a * 16 + orow;
#pragma unroll
        for (int b = 0; b < 4; ++b) {
            int j = j0 + wj + b * 16 + fr;
            float bj = bias[j];
#pragma unroll
            for (int r = 0; r < 4; ++r)
                D[(size_t)(ibx + r) * C_DIM + j] = __float2bfloat16(acc[a][b][r] + bj);
        }
    }
}

// ---------------------------------------------------------------------------
// prep: blocks [0,4608) transpose+cast inputs (z<8 locx->Xl else glox->Xg);
//       blocks [4608,5632) cast the 4 weight mats to contiguous bf16.
// ---------------------------------------------------------------------------
__global__ __launch_bounds__(256)
void prep(const float* __restrict__ locx, const float* __restrict__ glox,
          __hip_bfloat16* __restrict__ Xl, __hip_bfloat16* __restrict__ Xg,
          const float* __restrict__ w0, const float* __restrict__ w1,
          const float* __restrict__ w2, const float* __restrict__ w3,
          __hip_bfloat16* __restrict__ wgt)
{
    const int lin = blockIdx.x;
    const int tid = threadIdx.x;

    if (lin < 4608) {
        __shared__ float t[64 * 65];
        const int z  = lin & 15;
        const int t2 = lin >> 4;
        const int c0 = (t2 & 7) * 64;
        const int n0 = (t2 >> 3) * 64;
        const size_t b = z & 7;
        const float* Xb = ((z < 8) ? locx : glox) + b * (size_t)C_DIM * N_PIX;
        __hip_bfloat16* Xt = (z < 8) ? Xl : Xg;

        const int n_l = tid & 63;
        const int c_b = tid >> 6;
#pragma unroll
        for (int s = 0; s < 16; ++s) {
            int c_l = c_b + s * 4;
            t[c_l * 65 + n_l] = Xb[(size_t)(c0 + c_l) * N_PIX + n0 + n_l];
        }
        __syncthreads();

        const int cc = (tid & 7) * 8;
        const int nb = tid >> 3;
#pragma unroll
        for (int it = 0; it < 2; ++it) {
            int n2 = nb + it * 32;
            union { __hip_bfloat16 h[8]; int4 v; } u;
#pragma unroll
            for (int w = 0; w < 8; ++w)
                u.h[w] = __float2bfloat16(t[(cc + w) * 65 + n2]);
            *(int4*)(&Xt[(b * N_PIX + n0 + n2) * C_DIM + c0 + cc]) = u.v;
        }
    } else {
        const int idx = lin - 4608;          // 0..1023
        const int w   = idx >> 8;            // 0..3
        const float* srcs[4] = {w0, w1, w2, w3};
        const int i = ((idx & 255) * 256 + tid) * 4;
        float4 f = *(const float4*)(srcs[w] + i);
        union { __hip_bfloat16 h[4]; s16x4 q; } u;
        u.h[0] = __float2bfloat16(f.x);
        u.h[1] = __float2bfloat16(f.y);
        u.h[2] = __float2bfloat16(f.z);
        u.h[3] = __float2bfloat16(f.w);
        *(s16x4*)(wgt + (size_t)w * C_DIM * C_DIM + i) = u.q;
    }
}

// ---------------------------------------------------------------------------
extern "C" void kernel_launch(void* const* d_in, const int* in_sizes, int n_in,
                              void* d_out, int out_size, void* d_ws, size_t ws_size,
                              hipStream_t stream)
{
    const float* locx = (const float*)d_in[0];
    const float* glox = (const float*)d_in[1];
    const float* Wq = (const float*)d_in[2];
    const float* bq = (const float*)d_in[3];
    const float* Wk = (const float*)d_in[4];
    const float* bk = (const float*)d_in[5];
    const float* Wv = (const float*)d_in[6];
    const float* bv = (const float*)d_in[7];
    const float* Wo = (const float*)d_in[8];
    const float* bo = (const float*)d_in[9];
    float* out = (float*)d_out;

    const int C = C_DIM, N = N_PIX;
    const size_t WB   = (size_t)C * C * 2;
    const size_t szX  = (size_t)N_BATCH * N * C * 2;   // 18.87 MB
    const size_t szP1 = (size_t)N * N * 2;
    const size_t szRP = (size_t)NJB * N_BATCH * N * 4;

    const size_t fixed = 4 * WB + 6 * szX + szRP;      // wgt + Xl,Xg,QKV(3),Vp + rp
    bool full = (ws_size >= fixed + 8 * szP1 + 4096);

    char* ws = (char*)d_ws;
    size_t off = 0;
    auto alloc = [&](size_t bytes) {
        char* p = ws + off;
        off += (bytes + 255) & ~(size_t)255;
        return p;
    };
    __hip_bfloat16* wgt = (__hip_bfloat16*)alloc(4 * WB);
    __hip_bfloat16* Xl  = (__hip_bfloat16*)alloc(szX);
    __hip_bfloat16* Xg  = (__hip_bfloat16*)alloc(szX);
    __hip_bfloat16* QKV = (__hip_bfloat16*)alloc(3 * szX);
    __hip_bfloat16* Vp  = (__hip_bfloat16*)alloc(szX);
    float*          rp  = (float*)alloc(szRP);
    __hip_bfloat16* Pu  = (__hip_bfloat16*)alloc(full ? 8 * szP1 : szP1);

    __hip_bfloat16* Qt = QKV;
    __hip_bfloat16* Kt = QKV + (size_t)N_BATCH * N * C;
    __hip_bfloat16* Vt = QKV + 2 * (size_t)N_BATCH * N * C;
    __hip_bfloat16* wo_b = wgt + 3 * (size_t)C * C;

    const dim3 blk(256);

    prep<<<dim3(5632), blk, 0, stream>>>(locx, glox, Xl, Xg, Wq, Wk, Wv, Wo, wgt);
    proj_qkv<<<dim3(24 * 72), blk, 0, stream>>>(Xl, Xg, wgt, bq, bk, bv, QKV);

    if (full) {
        s_vp<8><<<dim3(8 * 99), dim3(512), 0, stream>>>(
            Qt, Kt, Pu, rp, wo_b, Vt, Vp, 0, (long)N * N);
        pv_out<8><<<dim3(8 * 144), blk, 0, stream>>>(
            Vp, Pu, out, bo, rp, 0, (long)N * N);
    } else {
        for (int r = 0; r < N_BATCH; ++r) {
            s_vp<1><<<dim3(99), dim3(512), 0, stream>>>(
                Qt, Kt, Pu, rp, wo_b, Vt, Vp, r, 0);
            pv_out<1><<<dim3(144), blk, 0, stream>>>(
                Vp, Pu, out, bo, rp, r, 0);
        }
    }
}